// Round 1
// baseline (217.660 us; speedup 1.0000x reference)
//
#include <hip/hip_runtime.h>
#include <cstdint>

#define BB 8
#define CC 128
#define HH 96
#define WW 160
#define HWsz (HH * WW)          // 15360
#define TH 8
#define TW 32
#define CSTEP 8
#define HALO_H (TH + 8)         // 16
#define HALO_W (TW + 8)         // 40
#define CH_WORDS (HALO_H * HALO_W)       // 640
#define CHUNK_WORDS (CSTEP * CH_WORDS)   // 5120
#define NWAVES 9
#define NTHREADS (NWAVES * 64)           // 576
#define WLOADS (CHUNK_WORDS / 64)        // 80 wave-sized loads per chunk
#define NCHUNKS (CC / CSTEP)             // 16
#define NBLOCKS (BB * (HH / TH) * (WW / TW))  // 480

__device__ __forceinline__ void g2l_dword(const float* g, float* l) {
  __builtin_amdgcn_global_load_lds((const __attribute__((address_space(1))) void*)g,
                                   (__attribute__((address_space(3))) void*)l,
                                   4, 0, 0);
}

extern "C" __global__ void __launch_bounds__(NTHREADS, 4)
corr81_kernel(const float* __restrict__ x1, const float* __restrict__ x2,
              float* __restrict__ out)
{
  __shared__ __align__(16) float lds[CHUNK_WORDS];  // 20 KB

  const int tid  = threadIdx.x;
  const int wv   = tid >> 6;     // dy index 0..8 (wave-uniform)
  const int lane = tid & 63;
  const int r    = lane >> 3;    // tile row 0..7
  const int j    = lane & 7;     // w-slot 0..7 (4 px each)

  const int bid = blockIdx.x;
  const int wt  = bid % (WW / TW);
  const int ht  = (bid / (WW / TW)) % (HH / TH);
  const int b   = bid / ((WW / TW) * (HH / TH));
  const int h0  = ht * TH;
  const int w0  = wt * TW;

  // Precompute per-lane x2 staging offsets (word offsets, constant across chunks;
  // replicate-pad clamping folded in here).
  uint32_t soff[9];
#pragma unroll
  for (int i = 0; i < 9; ++i) {
    const int idx = wv + 9 * i;          // wave-load slot 0..80
    const int e   = idx * 64 + lane;     // LDS word this lane fills
    const int ci  = e / CH_WORDS;        // channel within chunk
    const int rem = e - ci * CH_WORDS;
    const int hr  = rem / HALO_W;        // halo row 0..15
    const int wh  = rem - hr * HALO_W;   // halo col 0..39
    int gh = h0 + hr - 4; gh = gh < 0 ? 0 : (gh > HH - 1 ? HH - 1 : gh);
    int gw = w0 + wh - 4; gw = gw < 0 ? 0 : (gw > WW - 1 ? WW - 1 : gw);
    soff[i] = (uint32_t)((ci * HH + gh) * WW + gw);
  }

  const float* x2b = x2 + (size_t)b * CC * HWsz;
  const float* x1b = x1 + (size_t)b * CC * HWsz + (size_t)(h0 + r) * WW + (w0 + 4 * j);

  float acc[9][4];
#pragma unroll
  for (int dx = 0; dx < 9; ++dx)
#pragma unroll
    for (int p = 0; p < 4; ++p) acc[dx][p] = 0.f;

  // this thread's x2 window row within the halo tile: global row h0+r+dy-4 -> halo row r+wv
  const int rowbase = (r + wv) * HALO_W + 4 * j;

  for (int chunk = 0; chunk < NCHUNKS; ++chunk) {
    const float* x2c = x2b + (size_t)chunk * (CSTEP * HWsz);
    // async-stage CSTEP channels of the x2 halo tile into LDS
#pragma unroll
    for (int i = 0; i < 9; ++i) {
      const int idx = wv + 9 * i;
      if (idx < WLOADS) {                 // wave-uniform predicate
        g2l_dword(x2c + soff[i], &lds[idx * 64]);
      }
    }
    __syncthreads();

#pragma unroll
    for (int ci = 0; ci < CSTEP; ++ci) {
      const float* x1c = x1b + (size_t)(chunk * CSTEP + ci) * HWsz;
      const float4 a4 = *(const float4*)x1c;           // global, L1-cached (shared by 9 dy-waves)
      const float av[4] = {a4.x, a4.y, a4.z, a4.w};
      const float4* wr = (const float4*)&lds[ci * CH_WORDS + rowbase];
      const float4 f0 = wr[0];
      const float4 f1 = wr[1];
      const float4 f2 = wr[2];
      const float w12[12] = {f0.x, f0.y, f0.z, f0.w,
                             f1.x, f1.y, f1.z, f1.w,
                             f2.x, f2.y, f2.z, f2.w};
#pragma unroll
      for (int dx = 0; dx < 9; ++dx)
#pragma unroll
        for (int p = 0; p < 4; ++p)
          acc[dx][p] = fmaf(av[p], w12[dx + p], acc[dx][p]);
    }
    __syncthreads();
  }

  // epilogue: out[((b*81 + wv*9+dx)*H + h0+r)*W + w0+4j ...], scaled by 1/num_chunks = 1/8
  float* op = out + (((size_t)b * 81 + (size_t)wv * 9) * HH + (h0 + r)) * WW + (w0 + 4 * j);
#pragma unroll
  for (int dx = 0; dx < 9; ++dx) {
    float4 v;
    v.x = acc[dx][0] * 0.125f;
    v.y = acc[dx][1] * 0.125f;
    v.z = acc[dx][2] * 0.125f;
    v.w = acc[dx][3] * 0.125f;
    *(float4*)(op + (size_t)dx * HWsz) = v;
  }
}

extern "C" void kernel_launch(void* const* d_in, const int* in_sizes, int n_in,
                              void* d_out, int out_size, void* d_ws, size_t ws_size,
                              hipStream_t stream) {
  const float* x1 = (const float*)d_in[0];
  const float* x2 = (const float*)d_in[1];
  float* out = (float*)d_out;
  corr81_kernel<<<dim3(NBLOCKS), dim3(NTHREADS), 0, stream>>>(x1, x2, out);
}